// Round 4
// baseline (2420.914 us; speedup 1.0000x reference)
//
#include <hip/hip_runtime.h>
#include <math.h>

#define FIN 500
#define NHID 64
#define NCLS 40
#define NLAYERS 8
#define CSHIFT 9                 // 512 rows per coarse bucket
#define CROWS (1 << CSHIFT)
#define PTILE 16384              // edges per partition block

typedef _Float16 half4 __attribute__((ext_vector_type(4)));

// ---------------- h0 = relu(x @ W_in + b_in) -> fp16 ----------------
__global__ __launch_bounds__(256) void k_gemm_in(
    const float* __restrict__ x, const float* __restrict__ W,
    const float* __restrict__ b, half4* __restrict__ h0h, int n) {
  __shared__ __align__(16) float xs[32 * 68];
  __shared__ __align__(16) float ws[32 * 64];
  const int tid = threadIdx.x;
  const int row0 = blockIdx.x * 64;
  const int cj = (tid & 15) * 4;
  const int ri = (tid >> 4) * 4;
  float acc[4][4] = {};
  for (int k0 = 0; k0 < FIN; k0 += 32) {
#pragma unroll
    for (int t = 0; t < 8; ++t) {
      int idx = tid + t * 256;
      int r = idx >> 5, k = idx & 31;
      int gr = row0 + r; if (gr >= n) gr = n - 1;
      int gk = k0 + k;
      xs[k * 68 + r] = (gk < FIN) ? x[(size_t)gr * FIN + gk] : 0.f;
    }
#pragma unroll
    for (int t = 0; t < 8; ++t) {
      int idx = tid + t * 256;
      int k = idx >> 6, j = idx & 63;
      int gk = k0 + k;
      ws[k * 64 + j] = (gk < FIN) ? W[gk * NHID + j] : 0.f;
    }
    __syncthreads();
#pragma unroll 8
    for (int k = 0; k < 32; ++k) {
      const float4 wv = *reinterpret_cast<const float4*>(&ws[k * 64 + cj]);
      const float4 xv = *reinterpret_cast<const float4*>(&xs[k * 68 + ri]);
      const float xa[4] = {xv.x, xv.y, xv.z, xv.w};
      const float wa[4] = {wv.x, wv.y, wv.z, wv.w};
#pragma unroll
      for (int i = 0; i < 4; ++i)
#pragma unroll
        for (int j = 0; j < 4; ++j) acc[i][j] += xa[i] * wa[j];
    }
    __syncthreads();
  }
  const float4 bv = *reinterpret_cast<const float4*>(&b[cj]);
  const float ba[4] = {bv.x, bv.y, bv.z, bv.w};
#pragma unroll
  for (int i = 0; i < 4; ++i) {
    int gr = row0 + ri + i;
    if (gr < n) {
      half4 hv;
      hv.x = (_Float16)fmaxf(acc[i][0] + ba[0], 0.f);
      hv.y = (_Float16)fmaxf(acc[i][1] + ba[1], 0.f);
      hv.z = (_Float16)fmaxf(acc[i][2] + ba[2], 0.f);
      hv.w = (_Float16)fmaxf(acc[i][3] + ba[3], 0.f);
      h0h[(size_t)gr * 16 + (cj >> 2)] = hv;
    }
  }
}

// ---------------- CSR build: histogram ----------------
__global__ __launch_bounds__(256) void k_hist(
    const int* __restrict__ row, int* __restrict__ cnt, int e_total) {
  int i = blockIdx.x * 256 + threadIdx.x;
  if (i < e_total) atomicAdd(&cnt[row[i]], 1);
}

// ---------------- CSR build: per-block sums ----------------
__global__ __launch_bounds__(256) void k_scan1(
    const int* __restrict__ cnt, int* __restrict__ bsum, int n) {
  __shared__ int wsum[4];
  const int tid = threadIdx.x;
  int base = blockIdx.x * 1024 + tid * 4;
  int s = 0;
#pragma unroll
  for (int t = 0; t < 4; ++t) {
    int idx = base + t;
    if (idx < n) s += cnt[idx];
  }
#pragma unroll
  for (int off = 1; off < 64; off <<= 1) s += __shfl_xor(s, off, 64);
  if ((tid & 63) == 0) wsum[tid >> 6] = s;
  __syncthreads();
  if (tid == 0) bsum[blockIdx.x] = wsum[0] + wsum[1] + wsum[2] + wsum[3];
}

// ---------------- CSR build: scan block sums ----------------
__global__ __launch_bounds__(1024) void k_scan2(
    int* __restrict__ bsum, int nb, int* __restrict__ ptr, int n) {
  __shared__ int sh[1024];
  const int t = threadIdx.x;
  sh[t] = (t < nb) ? bsum[t] : 0;
  __syncthreads();
  if (t == 0) {
    int run = 0;
    for (int i = 0; i < nb; ++i) { int v = sh[i]; sh[i] = run; run += v; }
    ptr[n] = run;
  }
  __syncthreads();
  if (t < nb) bsum[t] = sh[t];
}

// ---------------- CSR build: exclusive scan -> ptr ----------------
__global__ __launch_bounds__(256) void k_scan3(
    const int* __restrict__ cnt_in, const int* __restrict__ bsum,
    int* __restrict__ ptr, int n) {
  __shared__ int wsum[4];
  const int tid = threadIdx.x;
  const int lane = tid & 63, wid = tid >> 6;
  int base = blockIdx.x * 1024 + tid * 4;
  int c[4]; int s = 0;
#pragma unroll
  for (int t = 0; t < 4; ++t) {
    int idx = base + t;
    c[t] = (idx < n) ? cnt_in[idx] : 0;
    s += c[t];
  }
  int incl = s;
#pragma unroll
  for (int off = 1; off < 64; off <<= 1) {
    int u = __shfl_up(incl, off, 64);
    if (lane >= off) incl += u;
  }
  if (lane == 63) wsum[wid] = incl;
  __syncthreads();
  int woff = 0;
  for (int i = 0; i < wid; ++i) woff += wsum[i];
  int run = incl - s + woff + bsum[blockIdx.x];
#pragma unroll
  for (int t = 0; t < 4; ++t) {
    int idx = base + t;
    if (idx < n) { ptr[idx] = run; run += c[t]; }
  }
}

// ---------------- coarse bucket cursors ----------------
__global__ __launch_bounds__(256) void k_binit2(
    const int* __restrict__ ptr, int* __restrict__ bcur, int nbC, int n) {
  int c = blockIdx.x * 256 + threadIdx.x;
  if (c < nbC) {
    int r = c << CSHIFT; if (r > n) r = n;
    bcur[c] = ptr[r];
  }
}

// ---------------- pass 1: block-local coarse partition ----------------
// Each block owns PTILE contiguous edges; LDS histogram over coarse buckets;
// ONE contiguous run per (block,bucket) reserved globally -> writes from one
// block land in one contiguous region in one time window (no cross-XCD line
// sharing, ~1x write amplification).
__global__ __launch_bounds__(256) void k_part2(
    const int* __restrict__ row, const int* __restrict__ col,
    const float* __restrict__ w, int* __restrict__ bcurG,
    int2* __restrict__ staged, int e_total, int nbC) {
  __shared__ int hist[256];
  __shared__ int cur[256];
  const int tid = threadIdx.x;
  const int e0 = blockIdx.x * PTILE;
  if (tid < nbC) hist[tid] = 0;
  __syncthreads();
  // phase A: histogram
  for (int t = 0; t < PTILE / 256; ++t) {
    int e = e0 + t * 256 + tid;
    if (e < e_total) atomicAdd(&hist[row[e] >> CSHIFT], 1);
  }
  __syncthreads();
  // reserve runs
  if (tid < nbC) {
    int h = hist[tid];
    cur[tid] = h ? atomicAdd(&bcurG[tid], h) : 0;
  }
  __syncthreads();
  // phase B: write into private runs
  for (int t = 0; t < PTILE / 256; ++t) {
    int e = e0 + t * 256 + tid;
    if (e < e_total) {
      int r = row[e];
      int pos = atomicAdd(&cur[r >> CSHIFT], 1);
      staged[pos] = make_int2(((r & (CROWS - 1)) << 17) | col[e], __float_as_int(w[e]));
    }
  }
}

// ---------------- pass 2: exact CSR placement within coarse bucket ----------------
// one block per coarse bucket; writes confined to its ~131KB window (one L2).
__global__ __launch_bounds__(256) void k_rebin2(
    const int* __restrict__ ptr, const int2* __restrict__ staged,
    int2* __restrict__ sorted, int n) {
  __shared__ int cur[CROWS];
  const int r0 = blockIdx.x << CSHIFT;
  const int rend = (r0 + CROWS < n) ? (r0 + CROWS) : n;
  for (int i = threadIdx.x; i < CROWS; i += 256) {
    int rr = r0 + i;
    cur[i] = (rr < n) ? ptr[rr] : 0;
  }
  __syncthreads();
  const int bstart = ptr[r0], bend = ptr[rend];
  for (int i = bstart + threadIdx.x; i < bend; i += 256) {
    int2 e = staged[i];
    int pos = atomicAdd(&cur[e.x >> 17], 1);
    sorted[pos] = make_int2(e.x & 0x1FFFF, e.y);
  }
}

// ---------------- fused: S = 0.9*spmm + 0.1*h0 ; h = relu(beta*(S@Wl)+(1-beta)*S) ----------------
__global__ __launch_bounds__(256) void k_slayer(
    const int* __restrict__ ptr, const int2* __restrict__ sorted,
    const half4* __restrict__ hin, const half4* __restrict__ h0h,
    const float* __restrict__ Wl, float* __restrict__ Af,
    half4* __restrict__ hout, float beta, int n, int write_f32) {
  __shared__ __align__(16) float st[64 * 68];   // S transposed [j][r]
  __shared__ __align__(16) float ws[64 * 64];   // Wl [k][j]
  const int tid = threadIdx.x;
  const int row0 = blockIdx.x * 64;
#pragma unroll
  for (int t = 0; t < 16; ++t) ws[tid + t * 256] = Wl[tid + t * 256];
  const int lane = tid & 63;
  const int wv = tid >> 6;        // wave 0..3
  const int sub = lane >> 4;      // edge slot
  const int fl = lane & 15;       // feature group
  // phase 1: SpMM for this wave's 16 rows
  for (int rr = 0; rr < 16; ++rr) {
    const int rloc = wv * 16 + rr;
    const int r = row0 + rloc;
    float4 acc = {0.f, 0.f, 0.f, 0.f};
    if (r < n) {
      const int s0 = ptr[r], s1 = ptr[r + 1];
      for (int e = s0 + sub; e < s1; e += 4) {
        int2 cw = sorted[e];
        float wvv = __int_as_float(cw.y);
        half4 hv = hin[(size_t)cw.x * 16 + fl];
        acc.x += wvv * (float)hv.x;
        acc.y += wvv * (float)hv.y;
        acc.z += wvv * (float)hv.z;
        acc.w += wvv * (float)hv.w;
      }
    }
#pragma unroll
    for (int off = 16; off < 64; off <<= 1) {
      acc.x += __shfl_xor(acc.x, off, 64);
      acc.y += __shfl_xor(acc.y, off, 64);
      acc.z += __shfl_xor(acc.z, off, 64);
      acc.w += __shfl_xor(acc.w, off, 64);
    }
    if (sub == 0) {
      float4 o = {0.f, 0.f, 0.f, 0.f};
      if (r < n) {
        half4 h0v = h0h[(size_t)r * 16 + fl];
        o.x = 0.9f * acc.x + 0.1f * (float)h0v.x;
        o.y = 0.9f * acc.y + 0.1f * (float)h0v.y;
        o.z = 0.9f * acc.z + 0.1f * (float)h0v.z;
        o.w = 0.9f * acc.w + 0.1f * (float)h0v.w;
      }
      st[(fl * 4 + 0) * 68 + rloc] = o.x;
      st[(fl * 4 + 1) * 68 + rloc] = o.y;
      st[(fl * 4 + 2) * 68 + rloc] = o.z;
      st[(fl * 4 + 3) * 68 + rloc] = o.w;
    }
  }
  __syncthreads();
  // phase 2: 64x64 GEMM from LDS
  const int cj = (tid & 15) * 4;
  const int ri = (tid >> 4) * 4;
  float acc[4][4] = {};
#pragma unroll 8
  for (int k = 0; k < 64; ++k) {
    const float4 wv4 = *reinterpret_cast<const float4*>(&ws[k * 64 + cj]);
    const float4 sv = *reinterpret_cast<const float4*>(&st[k * 68 + ri]);
    const float sa[4] = {sv.x, sv.y, sv.z, sv.w};
    const float wa[4] = {wv4.x, wv4.y, wv4.z, wv4.w};
#pragma unroll
    for (int i = 0; i < 4; ++i)
#pragma unroll
      for (int j = 0; j < 4; ++j) acc[i][j] += sa[i] * wa[j];
  }
  const float g = 1.f - beta;
#pragma unroll
  for (int i = 0; i < 4; ++i) {
    int gr = row0 + ri + i;
    if (gr < n) {
      float4 o;
      o.x = fmaxf(beta * acc[i][0] + g * st[(cj + 0) * 68 + (ri + i)], 0.f);
      o.y = fmaxf(beta * acc[i][1] + g * st[(cj + 1) * 68 + (ri + i)], 0.f);
      o.z = fmaxf(beta * acc[i][2] + g * st[(cj + 2) * 68 + (ri + i)], 0.f);
      o.w = fmaxf(beta * acc[i][3] + g * st[(cj + 3) * 68 + (ri + i)], 0.f);
      half4 hv; hv.x = (_Float16)o.x; hv.y = (_Float16)o.y;
      hv.z = (_Float16)o.z; hv.w = (_Float16)o.w;
      hout[(size_t)gr * 16 + (cj >> 2)] = hv;
      if (write_f32) *reinterpret_cast<float4*>(&Af[(size_t)gr * NHID + cj]) = o;
    }
  }
}

// ---------------- out = log_softmax(h @ W_out + b_out) ----------------
__global__ __launch_bounds__(256) void k_out(
    const float* __restrict__ h, const float* __restrict__ Wo,
    const float* __restrict__ bo, float* __restrict__ out, int n) {
  const int lane = threadIdx.x & 63;
  const int r = blockIdx.x * 4 + (threadIdx.x >> 6);
  if (r >= n) return;
  const float hv = h[(size_t)r * NHID + lane];
  const int j = (lane < NCLS) ? lane : (NCLS - 1);
  float acc = bo[j];
#pragma unroll 16
  for (int k = 0; k < NHID; ++k) {
    float hk = __shfl(hv, k, 64);
    acc += hk * Wo[k * NCLS + j];
  }
  float v = (lane < NCLS) ? acc : -INFINITY;
  float m = v;
#pragma unroll
  for (int off = 32; off; off >>= 1) m = fmaxf(m, __shfl_xor(m, off, 64));
  float e = (lane < NCLS) ? expf(acc - m) : 0.f;
  float s = e;
#pragma unroll
  for (int off = 32; off; off >>= 1) s += __shfl_xor(s, off, 64);
  if (lane < NCLS) out[(size_t)r * NCLS + lane] = acc - m - logf(s);
}

extern "C" void kernel_launch(void* const* d_in, const int* in_sizes, int n_in,
                              void* d_out, int out_size, void* d_ws, size_t ws_size,
                              hipStream_t stream) {
  const float* x  = (const float*)d_in[0];
  const int* row  = (const int*)d_in[1];
  const int* col  = (const int*)d_in[2];
  const float* ew = (const float*)d_in[3];
  const float* Wi = (const float*)d_in[4];
  const float* bi = (const float*)d_in[5];
  const float* Wc = (const float*)d_in[6];
  const float* Wo = (const float*)d_in[7];
  const float* bo = (const float*)d_in[8];
  float* out = (float*)d_out;

  const int n = in_sizes[0] / FIN;   // 100000
  const int E = in_sizes[1];         // 3200000

  // workspace layout (~90 MB)
  half4* h0h   = (half4*)d_ws;                          // n*64 f16
  half4* hhA   = h0h + (size_t)n * 16;                  // n*64 f16
  half4* hhB   = hhA + (size_t)n * 16;                  // n*64 f16
  float* A     = (float*)(hhB + (size_t)n * 16);        // n*64 f32 (final h; aliased as staged)
  int2*  staged= (int2*)A;                              // E int2 (E*8 == n*64*4 here)
  int2*  sorted= (int2*)(A + (size_t)n * NHID);         // E int2
  int*   ptr   = (int*)(sorted + E);                    // n+1
  int*   cur   = ptr + (n + 1);                         // n (histogram)
  int*   bsum  = cur + n;                               // up to 1024
  int*   bcur  = bsum + 1024;                           // coarse cursors

  const int nb = (n + 1023) / 1024;
  const int nbC = (n + CROWS - 1) >> CSHIFT;            // 196
  const int nPB = (E + PTILE - 1) / PTILE;              // 196
  dim3 blk(256);

  // ---- CSR build (amortized over 8 SpMM layers) ----
  hipMemsetAsync(cur, 0, (size_t)n * sizeof(int), stream);
  k_hist<<<dim3((E + 255) / 256), blk, 0, stream>>>(row, cur, E);
  k_scan1<<<dim3(nb), blk, 0, stream>>>(cur, bsum, n);
  k_scan2<<<dim3(1), dim3(1024), 0, stream>>>(bsum, nb, ptr, n);
  k_scan3<<<dim3(nb), blk, 0, stream>>>(cur, bsum, ptr, n);
  k_binit2<<<dim3((nbC + 255) / 256), blk, 0, stream>>>(ptr, bcur, nbC, n);
  k_part2<<<dim3(nPB), blk, 0, stream>>>(row, col, ew, bcur, staged, E, nbC);
  k_rebin2<<<dim3(nbC), blk, 0, stream>>>(ptr, staged, sorted, n);

  // ---- dense input projection ----
  k_gemm_in<<<dim3((n + 63) / 64), blk, 0, stream>>>(x, Wi, bi, h0h, n);

  // ---- 8 fused GCNII layers ----
  const half4* hin = h0h;
  for (int l = 0; l < NLAYERS; ++l) {
    half4* hout = (l & 1) ? hhB : hhA;
    float beta = logf(0.5f / (float)(l + 1) + 1.f);
    k_slayer<<<dim3((n + 63) / 64), blk, 0, stream>>>(
        ptr, sorted, hin, h0h, Wc + (size_t)l * NHID * NHID, A, hout, beta, n,
        (l == NLAYERS - 1) ? 1 : 0);
    hin = hout;
  }
  k_out<<<dim3((n + 3) / 4), blk, 0, stream>>>(A, Wo, bo, out, n);
}

// Round 5
// 1619.172 us; speedup vs baseline: 1.4952x; 1.4952x over previous
//
#include <hip/hip_runtime.h>
#include <math.h>

#define FIN 500
#define NHID 64
#define NCLS 40
#define NLAYERS 8
#define CSHIFT 9                 // 512 rows per coarse bucket
#define CROWS (1 << CSHIFT)
#define PTILE 16384              // edges per partition block

typedef _Float16 half4 __attribute__((ext_vector_type(4)));

// swizzled LDS index for transposed [k][r] tiles, stride 68:
// element (k,r) at k*68 + (r ^ ((k>>2 & 7)<<2)).  Store: 2 lanes/bank (free).
// Read (float4 along r): 16B-aligned since swizzle flips only bits 2..4 of r.

// ---------------- h0 = relu(x @ W_in + b_in) -> fp16 ----------------
__global__ __launch_bounds__(256) void k_gemm_in(
    const float* __restrict__ x, const float* __restrict__ W,
    const float* __restrict__ b, half4* __restrict__ h0h, int n) {
  __shared__ __align__(16) float xs[32 * 68];
  __shared__ __align__(16) float ws[32 * 64];
  const int tid = threadIdx.x;
  const int row0 = blockIdx.x * 64;
  const int cj = (tid & 15) * 4;
  const int ri = (tid >> 4) * 4;
  float acc[4][4] = {};
  for (int k0 = 0; k0 < 512; k0 += 32) {
    // x tile: 64 rows x 32 k, float4 loads along k, swizzled transposed store
#pragma unroll
    for (int t = 0; t < 2; ++t) {
      int idx = tid + t * 256;          // 0..511
      int q = idx & 7;                  // k-quad
      int r = idx >> 3;                 // 0..63
      int gr = row0 + r; if (gr >= n) gr = n - 1;
      int gk = k0 + q * 4;
      float4 v;
      if (gk + 3 < FIN) {
        v = *reinterpret_cast<const float4*>(&x[(size_t)gr * FIN + gk]);
      } else {
        v.x = (gk + 0 < FIN) ? x[(size_t)gr * FIN + gk + 0] : 0.f;
        v.y = (gk + 1 < FIN) ? x[(size_t)gr * FIN + gk + 1] : 0.f;
        v.z = (gk + 2 < FIN) ? x[(size_t)gr * FIN + gk + 2] : 0.f;
        v.w = (gk + 3 < FIN) ? x[(size_t)gr * FIN + gk + 3] : 0.f;
      }
      int rr = r ^ (q << 2);            // swizzle (q = k>>2, q<8)
      xs[(q * 4 + 0) * 68 + rr] = v.x;
      xs[(q * 4 + 1) * 68 + rr] = v.y;
      xs[(q * 4 + 2) * 68 + rr] = v.z;
      xs[(q * 4 + 3) * 68 + rr] = v.w;
    }
    // W tile: 32 k x 64 j, float4, natural layout (conflict-free)
#pragma unroll
    for (int t = 0; t < 2; ++t) {
      int idx = tid + t * 256;          // 0..511
      int q = idx & 15;                 // j-quad
      int k = idx >> 4;                 // 0..31
      int gk = k0 + k;
      float4 wv = {0.f, 0.f, 0.f, 0.f};
      if (gk < FIN) wv = *reinterpret_cast<const float4*>(&W[(size_t)gk * NHID + q * 4]);
      *reinterpret_cast<float4*>(&ws[k * 64 + q * 4]) = wv;
    }
    __syncthreads();
#pragma unroll 8
    for (int k = 0; k < 32; ++k) {
      const int s = ((k >> 2) & 7) << 2;
      const float4 wv = *reinterpret_cast<const float4*>(&ws[k * 64 + cj]);
      const float4 xv = *reinterpret_cast<const float4*>(&xs[k * 68 + (ri ^ s)]);
      const float xa[4] = {xv.x, xv.y, xv.z, xv.w};
      const float wa[4] = {wv.x, wv.y, wv.z, wv.w};
#pragma unroll
      for (int i = 0; i < 4; ++i)
#pragma unroll
        for (int j = 0; j < 4; ++j) acc[i][j] += xa[i] * wa[j];
    }
    __syncthreads();
  }
  const float4 bv = *reinterpret_cast<const float4*>(&b[cj]);
  const float ba[4] = {bv.x, bv.y, bv.z, bv.w};
#pragma unroll
  for (int i = 0; i < 4; ++i) {
    int gr = row0 + ri + i;
    if (gr < n) {
      half4 hv;
      hv.x = (_Float16)fmaxf(acc[i][0] + ba[0], 0.f);
      hv.y = (_Float16)fmaxf(acc[i][1] + ba[1], 0.f);
      hv.z = (_Float16)fmaxf(acc[i][2] + ba[2], 0.f);
      hv.w = (_Float16)fmaxf(acc[i][3] + ba[3], 0.f);
      h0h[(size_t)gr * 16 + (cj >> 2)] = hv;
    }
  }
}

// ---------------- CSR build: histogram ----------------
__global__ __launch_bounds__(256) void k_hist(
    const int* __restrict__ row, int* __restrict__ cnt, int e_total) {
  int i = blockIdx.x * 256 + threadIdx.x;
  if (i < e_total) atomicAdd(&cnt[row[i]], 1);
}

// ---------------- CSR build: per-block sums ----------------
__global__ __launch_bounds__(256) void k_scan1(
    const int* __restrict__ cnt, int* __restrict__ bsum, int n) {
  __shared__ int wsum[4];
  const int tid = threadIdx.x;
  int base = blockIdx.x * 1024 + tid * 4;
  int s = 0;
#pragma unroll
  for (int t = 0; t < 4; ++t) {
    int idx = base + t;
    if (idx < n) s += cnt[idx];
  }
#pragma unroll
  for (int off = 1; off < 64; off <<= 1) s += __shfl_xor(s, off, 64);
  if ((tid & 63) == 0) wsum[tid >> 6] = s;
  __syncthreads();
  if (tid == 0) bsum[blockIdx.x] = wsum[0] + wsum[1] + wsum[2] + wsum[3];
}

// ---------------- CSR build: scan block sums ----------------
__global__ __launch_bounds__(1024) void k_scan2(
    int* __restrict__ bsum, int nb, int* __restrict__ ptr, int n) {
  __shared__ int sh[1024];
  const int t = threadIdx.x;
  sh[t] = (t < nb) ? bsum[t] : 0;
  __syncthreads();
  if (t == 0) {
    int run = 0;
    for (int i = 0; i < nb; ++i) { int v = sh[i]; sh[i] = run; run += v; }
    ptr[n] = run;
  }
  __syncthreads();
  if (t < nb) bsum[t] = sh[t];
}

// ---------------- CSR build: exclusive scan -> ptr ----------------
__global__ __launch_bounds__(256) void k_scan3(
    const int* __restrict__ cnt_in, const int* __restrict__ bsum,
    int* __restrict__ ptr, int n) {
  __shared__ int wsum[4];
  const int tid = threadIdx.x;
  const int lane = tid & 63, wid = tid >> 6;
  int base = blockIdx.x * 1024 + tid * 4;
  int c[4]; int s = 0;
#pragma unroll
  for (int t = 0; t < 4; ++t) {
    int idx = base + t;
    c[t] = (idx < n) ? cnt_in[idx] : 0;
    s += c[t];
  }
  int incl = s;
#pragma unroll
  for (int off = 1; off < 64; off <<= 1) {
    int u = __shfl_up(incl, off, 64);
    if (lane >= off) incl += u;
  }
  if (lane == 63) wsum[wid] = incl;
  __syncthreads();
  int woff = 0;
  for (int i = 0; i < wid; ++i) woff += wsum[i];
  int run = incl - s + woff + bsum[blockIdx.x];
#pragma unroll
  for (int t = 0; t < 4; ++t) {
    int idx = base + t;
    if (idx < n) { ptr[idx] = run; run += c[t]; }
  }
}

// ---------------- coarse bucket cursors ----------------
__global__ __launch_bounds__(256) void k_binit2(
    const int* __restrict__ ptr, int* __restrict__ bcur, int nbC, int n) {
  int c = blockIdx.x * 256 + threadIdx.x;
  if (c < nbC) {
    int r = c << CSHIFT; if (r > n) r = n;
    bcur[c] = ptr[r];
  }
}

// ---------------- pass 1: block-local coarse partition ----------------
__global__ __launch_bounds__(256) void k_part2(
    const int* __restrict__ row, const int* __restrict__ col,
    const float* __restrict__ w, int* __restrict__ bcurG,
    int2* __restrict__ staged, int e_total, int nbC) {
  __shared__ int hist[256];
  __shared__ int cur[256];
  const int tid = threadIdx.x;
  const int e0 = blockIdx.x * PTILE;
  if (tid < nbC) hist[tid] = 0;
  __syncthreads();
  for (int t = 0; t < PTILE / 256; ++t) {
    int e = e0 + t * 256 + tid;
    if (e < e_total) atomicAdd(&hist[row[e] >> CSHIFT], 1);
  }
  __syncthreads();
  if (tid < nbC) {
    int h = hist[tid];
    cur[tid] = h ? atomicAdd(&bcurG[tid], h) : 0;
  }
  __syncthreads();
  for (int t = 0; t < PTILE / 256; ++t) {
    int e = e0 + t * 256 + tid;
    if (e < e_total) {
      int r = row[e];
      int pos = atomicAdd(&cur[r >> CSHIFT], 1);
      staged[pos] = make_int2(((r & (CROWS - 1)) << 17) | col[e], __float_as_int(w[e]));
    }
  }
}

// ---------------- pass 2: exact CSR placement within coarse bucket ----------------
__global__ __launch_bounds__(256) void k_rebin2(
    const int* __restrict__ ptr, const int2* __restrict__ staged,
    int2* __restrict__ sorted, int n) {
  __shared__ int cur[CROWS];
  const int r0 = blockIdx.x << CSHIFT;
  const int rend = (r0 + CROWS < n) ? (r0 + CROWS) : n;
  for (int i = threadIdx.x; i < CROWS; i += 256) {
    int rr = r0 + i;
    cur[i] = (rr < n) ? ptr[rr] : 0;
  }
  __syncthreads();
  const int bstart = ptr[r0], bend = ptr[rend];
  for (int i = bstart + threadIdx.x; i < bend; i += 256) {
    int2 e = staged[i];
    int pos = atomicAdd(&cur[e.x >> 17], 1);
    sorted[pos] = make_int2(e.x & 0x1FFFF, e.y);
  }
}

// ---------------- SpMM (CSR, fp16 gather) + support blend -> S fp32 ----------------
// one row per wave, no LDS, full occupancy for latency hiding.
__global__ __launch_bounds__(256) void k_spmm_csr(
    const int* __restrict__ ptr, const int2* __restrict__ sorted,
    const half4* __restrict__ hh, const half4* __restrict__ h0h,
    float* __restrict__ S, int n) {
  const int r = blockIdx.x * 4 + (threadIdx.x >> 6);
  if (r >= n) return;
  const int lane = threadIdx.x & 63;
  const int sub = lane >> 4;       // edge slot 0..3
  const int fl = lane & 15;        // feature group
  const int start = ptr[r], end = ptr[r + 1];
  float4 acc = {0.f, 0.f, 0.f, 0.f};
  for (int e = start + sub; e < end; e += 4) {
    int2 cw = sorted[e];
    float wv = __int_as_float(cw.y);
    half4 hv = hh[(size_t)cw.x * 16 + fl];
    acc.x += wv * (float)hv.x;
    acc.y += wv * (float)hv.y;
    acc.z += wv * (float)hv.z;
    acc.w += wv * (float)hv.w;
  }
#pragma unroll
  for (int off = 16; off < 64; off <<= 1) {
    acc.x += __shfl_xor(acc.x, off, 64);
    acc.y += __shfl_xor(acc.y, off, 64);
    acc.z += __shfl_xor(acc.z, off, 64);
    acc.w += __shfl_xor(acc.w, off, 64);
  }
  if (sub == 0) {
    half4 h0v = h0h[(size_t)r * 16 + fl];
    float4 o;
    o.x = 0.9f * acc.x + 0.1f * (float)h0v.x;
    o.y = 0.9f * acc.y + 0.1f * (float)h0v.y;
    o.z = 0.9f * acc.z + 0.1f * (float)h0v.z;
    o.w = 0.9f * acc.w + 0.1f * (float)h0v.w;
    *reinterpret_cast<float4*>(&S[(size_t)r * NHID + fl * 4]) = o;
  }
}

// ---------------- h = relu(beta*(S@Wl) + (1-beta)*S) -> fp16 (+fp32 last) ----------------
__global__ __launch_bounds__(256) void k_layer(
    const float* __restrict__ S, const float* __restrict__ Wl,
    float* __restrict__ Af, half4* __restrict__ hout,
    float beta, int n, int write_f32) {
  __shared__ __align__(16) float st[64 * 68];   // transposed [j][r], swizzled
  __shared__ __align__(16) float ws[64 * 64];
  const int tid = threadIdx.x;
  const int row0 = blockIdx.x * 64;
#pragma unroll
  for (int t = 0; t < 4; ++t) {
    int idx = tid + t * 256;          // 0..1023
    int q = idx & 15;                 // j-quad
    int r = idx >> 4;                 // 0..63
    int gr = row0 + r; if (gr >= n) gr = n - 1;
    float4 v = *reinterpret_cast<const float4*>(&S[(size_t)gr * NHID + q * 4]);
    int rr = r ^ ((q & 7) << 2);
    st[(q * 4 + 0) * 68 + rr] = v.x;
    st[(q * 4 + 1) * 68 + rr] = v.y;
    st[(q * 4 + 2) * 68 + rr] = v.z;
    st[(q * 4 + 3) * 68 + rr] = v.w;
    *reinterpret_cast<float4*>(&ws[idx * 4]) = *reinterpret_cast<const float4*>(&Wl[idx * 4]);
  }
  __syncthreads();
  const int cj = (tid & 15) * 4;
  const int ri = (tid >> 4) * 4;
  float acc[4][4] = {};
#pragma unroll 8
  for (int k = 0; k < 64; ++k) {
    const int s = ((k >> 2) & 7) << 2;
    const float4 wv = *reinterpret_cast<const float4*>(&ws[k * 64 + cj]);
    const float4 sv = *reinterpret_cast<const float4*>(&st[k * 68 + (ri ^ s)]);
    const float sa[4] = {sv.x, sv.y, sv.z, sv.w};
    const float wa[4] = {wv.x, wv.y, wv.z, wv.w};
#pragma unroll
    for (int i = 0; i < 4; ++i)
#pragma unroll
      for (int j = 0; j < 4; ++j) acc[i][j] += sa[i] * wa[j];
  }
  const float g = 1.f - beta;
  const int sw = ((tid & 15) & 7) << 2;   // swizzle for columns cj..cj+3 (k>>2 == tid&15)
#pragma unroll
  for (int i = 0; i < 4; ++i) {
    int gr = row0 + ri + i;
    if (gr < n) {
      float4 o;
      o.x = fmaxf(beta * acc[i][0] + g * st[(cj + 0) * 68 + ((ri + i) ^ sw)], 0.f);
      o.y = fmaxf(beta * acc[i][1] + g * st[(cj + 1) * 68 + ((ri + i) ^ sw)], 0.f);
      o.z = fmaxf(beta * acc[i][2] + g * st[(cj + 2) * 68 + ((ri + i) ^ sw)], 0.f);
      o.w = fmaxf(beta * acc[i][3] + g * st[(cj + 3) * 68 + ((ri + i) ^ sw)], 0.f);
      half4 hv; hv.x = (_Float16)o.x; hv.y = (_Float16)o.y;
      hv.z = (_Float16)o.z; hv.w = (_Float16)o.w;
      hout[(size_t)gr * 16 + (cj >> 2)] = hv;
      if (write_f32) *reinterpret_cast<float4*>(&Af[(size_t)gr * NHID + cj]) = o;
    }
  }
}

// ---------------- out = log_softmax(h @ W_out + b_out) ----------------
__global__ __launch_bounds__(256) void k_out(
    const float* __restrict__ h, const float* __restrict__ Wo,
    const float* __restrict__ bo, float* __restrict__ out, int n) {
  const int lane = threadIdx.x & 63;
  const int r = blockIdx.x * 4 + (threadIdx.x >> 6);
  if (r >= n) return;
  const float hv = h[(size_t)r * NHID + lane];
  const int j = (lane < NCLS) ? lane : (NCLS - 1);
  float acc = bo[j];
#pragma unroll 16
  for (int k = 0; k < NHID; ++k) {
    float hk = __shfl(hv, k, 64);
    acc += hk * Wo[k * NCLS + j];
  }
  float v = (lane < NCLS) ? acc : -INFINITY;
  float m = v;
#pragma unroll
  for (int off = 32; off; off >>= 1) m = fmaxf(m, __shfl_xor(m, off, 64));
  float e = (lane < NCLS) ? expf(acc - m) : 0.f;
  float s = e;
#pragma unroll
  for (int off = 32; off; off >>= 1) s += __shfl_xor(s, off, 64);
  if (lane < NCLS) out[(size_t)r * NCLS + lane] = acc - m - logf(s);
}

extern "C" void kernel_launch(void* const* d_in, const int* in_sizes, int n_in,
                              void* d_out, int out_size, void* d_ws, size_t ws_size,
                              hipStream_t stream) {
  const float* x  = (const float*)d_in[0];
  const int* row  = (const int*)d_in[1];
  const int* col  = (const int*)d_in[2];
  const float* ew = (const float*)d_in[3];
  const float* Wi = (const float*)d_in[4];
  const float* bi = (const float*)d_in[5];
  const float* Wc = (const float*)d_in[6];
  const float* Wo = (const float*)d_in[7];
  const float* bo = (const float*)d_in[8];
  float* out = (float*)d_out;

  const int n = in_sizes[0] / FIN;   // 100000
  const int E = in_sizes[1];         // 3200000

  // workspace layout
  half4* h0h   = (half4*)d_ws;                          // n*64 f16
  half4* hhA   = h0h + (size_t)n * 16;                  // n*64 f16
  half4* hhB   = hhA + (size_t)n * 16;                  // n*64 f16
  float* A     = (float*)(hhB + (size_t)n * 16);        // n*64 f32 S-buffer; aliased as staged
  int2*  staged= (int2*)A;                              // E int2 (consumed before layers)
  int2*  sorted= (int2*)(A + (size_t)n * NHID);         // E int2
  int*   ptr   = (int*)(sorted + E);                    // n+1
  int*   cur   = ptr + (n + 1);                         // n (histogram)
  int*   bsum  = cur + n;                               // up to 1024
  int*   bcur  = bsum + 1024;                           // coarse cursors

  const int nb = (n + 1023) / 1024;
  const int nbC = (n + CROWS - 1) >> CSHIFT;
  const int nPB = (E + PTILE - 1) / PTILE;
  dim3 blk(256);

  // ---- CSR build ----
  hipMemsetAsync(cur, 0, (size_t)n * sizeof(int), stream);
  k_hist<<<dim3((E + 255) / 256), blk, 0, stream>>>(row, cur, E);
  k_scan1<<<dim3(nb), blk, 0, stream>>>(cur, bsum, n);
  k_scan2<<<dim3(1), dim3(1024), 0, stream>>>(bsum, nb, ptr, n);
  k_scan3<<<dim3(nb), blk, 0, stream>>>(cur, bsum, ptr, n);
  k_binit2<<<dim3((nbC + 255) / 256), blk, 0, stream>>>(ptr, bcur, nbC, n);
  k_part2<<<dim3(nPB), blk, 0, stream>>>(row, col, ew, bcur, staged, E, nbC);
  k_rebin2<<<dim3(nbC), blk, 0, stream>>>(ptr, staged, sorted, n);

  // ---- dense input projection ----
  k_gemm_in<<<dim3((n + 63) / 64), blk, 0, stream>>>(x, Wi, bi, h0h, n);

  // ---- 8 GCNII layers (split spmm / dense for occupancy) ----
  const half4* hin = h0h;
  for (int l = 0; l < NLAYERS; ++l) {
    half4* hout = (l & 1) ? hhB : hhA;
    k_spmm_csr<<<dim3((n + 3) / 4), blk, 0, stream>>>(ptr, sorted, hin, h0h, A, n);
    float beta = logf(0.5f / (float)(l + 1) + 1.f);
    k_layer<<<dim3((n + 63) / 64), blk, 0, stream>>>(
        A, Wc + (size_t)l * NHID * NHID, A, hout, beta, n, (l == NLAYERS - 1) ? 1 : 0);
    hin = hout;
  }
  k_out<<<dim3((n + 3) / 4), blk, 0, stream>>>(A, Wo, bo, out, n);
}

// Round 6
// 1283.321 us; speedup vs baseline: 1.8864x; 1.2617x over previous
//
#include <hip/hip_runtime.h>
#include <math.h>

#define FIN 500
#define NHID 64
#define NCLS 40
#define NLAYERS 8
#define CSHIFT 9                 // 512 rows per coarse bucket
#define CROWS (1 << CSHIFT)
#define PTILE 16384              // edges per partition block

typedef _Float16 half4 __attribute__((ext_vector_type(4)));
typedef _Float16 half8 __attribute__((ext_vector_type(8)));

// swizzled LDS index for transposed [k][r] tiles, stride 68:
// element (k,r) at k*68 + (r ^ ((k>>2 & 7)<<2)).  2 lanes/bank (free, m136).

// ---------------- h0 = relu(x @ W_in + b_in) -> fp16 ----------------
__global__ __launch_bounds__(256) void k_gemm_in(
    const float* __restrict__ x, const float* __restrict__ W,
    const float* __restrict__ b, half4* __restrict__ h0h, int n) {
  __shared__ __align__(16) float xs[32 * 68];
  __shared__ __align__(16) float ws[32 * 64];
  const int tid = threadIdx.x;
  const int row0 = blockIdx.x * 64;
  const int cj = (tid & 15) * 4;
  const int ri = (tid >> 4) * 4;
  float acc[4][4] = {};
  for (int k0 = 0; k0 < 512; k0 += 32) {
#pragma unroll
    for (int t = 0; t < 2; ++t) {
      int idx = tid + t * 256;          // 0..511
      int q = idx & 7;                  // k-quad
      int r = idx >> 3;                 // 0..63
      int gr = row0 + r; if (gr >= n) gr = n - 1;
      int gk = k0 + q * 4;
      float4 v;
      if (gk + 3 < FIN) {
        v = *reinterpret_cast<const float4*>(&x[(size_t)gr * FIN + gk]);
      } else {
        v.x = (gk + 0 < FIN) ? x[(size_t)gr * FIN + gk + 0] : 0.f;
        v.y = (gk + 1 < FIN) ? x[(size_t)gr * FIN + gk + 1] : 0.f;
        v.z = (gk + 2 < FIN) ? x[(size_t)gr * FIN + gk + 2] : 0.f;
        v.w = (gk + 3 < FIN) ? x[(size_t)gr * FIN + gk + 3] : 0.f;
      }
      int rr = r ^ (q << 2);
      xs[(q * 4 + 0) * 68 + rr] = v.x;
      xs[(q * 4 + 1) * 68 + rr] = v.y;
      xs[(q * 4 + 2) * 68 + rr] = v.z;
      xs[(q * 4 + 3) * 68 + rr] = v.w;
    }
#pragma unroll
    for (int t = 0; t < 2; ++t) {
      int idx = tid + t * 256;
      int q = idx & 15;
      int k = idx >> 4;
      int gk = k0 + k;
      float4 wv = {0.f, 0.f, 0.f, 0.f};
      if (gk < FIN) wv = *reinterpret_cast<const float4*>(&W[(size_t)gk * NHID + q * 4]);
      *reinterpret_cast<float4*>(&ws[k * 64 + q * 4]) = wv;
    }
    __syncthreads();
#pragma unroll 8
    for (int k = 0; k < 32; ++k) {
      const int s = ((k >> 2) & 7) << 2;
      const float4 wv = *reinterpret_cast<const float4*>(&ws[k * 64 + cj]);
      const float4 xv = *reinterpret_cast<const float4*>(&xs[k * 68 + (ri ^ s)]);
      const float xa[4] = {xv.x, xv.y, xv.z, xv.w};
      const float wa[4] = {wv.x, wv.y, wv.z, wv.w};
#pragma unroll
      for (int i = 0; i < 4; ++i)
#pragma unroll
        for (int j = 0; j < 4; ++j) acc[i][j] += xa[i] * wa[j];
    }
    __syncthreads();
  }
  const float4 bv = *reinterpret_cast<const float4*>(&b[cj]);
  const float ba[4] = {bv.x, bv.y, bv.z, bv.w};
#pragma unroll
  for (int i = 0; i < 4; ++i) {
    int gr = row0 + ri + i;
    if (gr < n) {
      half4 hv;
      hv.x = (_Float16)fmaxf(acc[i][0] + ba[0], 0.f);
      hv.y = (_Float16)fmaxf(acc[i][1] + ba[1], 0.f);
      hv.z = (_Float16)fmaxf(acc[i][2] + ba[2], 0.f);
      hv.w = (_Float16)fmaxf(acc[i][3] + ba[3], 0.f);
      h0h[(size_t)gr * 16 + (cj >> 2)] = hv;
    }
  }
}

// ---------------- coarse histogram: 196 buckets, LDS-privatized ----------------
__global__ __launch_bounds__(256) void k_chist(
    const int* __restrict__ row, int* __restrict__ ccnt, int e_total) {
  __shared__ int hist[256];
  const int tid = threadIdx.x;
  hist[tid] = 0;
  __syncthreads();
  const int e0 = blockIdx.x * PTILE;
  for (int t = 0; t < PTILE / 256; ++t) {
    int e = e0 + t * 256 + tid;
    if (e < e_total) atomicAdd(&hist[row[e] >> CSHIFT], 1);
  }
  __syncthreads();
  if (hist[tid]) atomicAdd(&ccnt[tid], hist[tid]);
}

// ---------------- scan 196 coarse counts -> cbase, bcur; ptr[n]=E ----------------
__global__ __launch_bounds__(256) void k_cscan(
    const int* __restrict__ ccnt, int* __restrict__ cbase,
    int* __restrict__ bcur, int* __restrict__ ptr, int nbC, int n, int E) {
  __shared__ int sh[257];
  const int t = threadIdx.x;
  sh[t] = (t < nbC) ? ccnt[t] : 0;
  __syncthreads();
  if (t == 0) {
    int run = 0;
    for (int i = 0; i < 256; ++i) { int v = sh[i]; sh[i] = run; run += v; }
    sh[256] = run;
  }
  __syncthreads();
  if (t <= nbC) cbase[t] = sh[t];
  if (t < nbC) bcur[t] = sh[t];
  if (t == 0) ptr[n] = E;
}

// ---------------- pass 1: block-local coarse partition ----------------
__global__ __launch_bounds__(256) void k_part2(
    const int* __restrict__ row, const int* __restrict__ col,
    const float* __restrict__ w, int* __restrict__ bcurG,
    int2* __restrict__ staged, int e_total, int nbC) {
  __shared__ int hist[256];
  __shared__ int cur[256];
  const int tid = threadIdx.x;
  const int e0 = blockIdx.x * PTILE;
  if (tid < nbC) hist[tid] = 0;
  __syncthreads();
  for (int t = 0; t < PTILE / 256; ++t) {
    int e = e0 + t * 256 + tid;
    if (e < e_total) atomicAdd(&hist[row[e] >> CSHIFT], 1);
  }
  __syncthreads();
  if (tid < nbC) {
    int h = hist[tid];
    cur[tid] = h ? atomicAdd(&bcurG[tid], h) : 0;
  }
  __syncthreads();
  for (int t = 0; t < PTILE / 256; ++t) {
    int e = e0 + t * 256 + tid;
    if (e < e_total) {
      int r = row[e];
      int pos = atomicAdd(&cur[r >> CSHIFT], 1);
      staged[pos] = make_int2(((r & (CROWS - 1)) << 17) | col[e], __float_as_int(w[e]));
    }
  }
}

// ---------------- pass 2: per-bucket row hist + scan -> ptr; place edges ----------------
__global__ __launch_bounds__(256) void k_rebin3(
    const int* __restrict__ cbase, const int2* __restrict__ staged,
    int2* __restrict__ sorted, int* __restrict__ ptr, int n) {
  __shared__ int rcnt[CROWS];
  __shared__ int cur[CROWS];
  __shared__ int wsum[4];
  const int tid = threadIdx.x;
  const int r0 = blockIdx.x << CSHIFT;
  const int bstart = cbase[blockIdx.x], bend = cbase[blockIdx.x + 1];
  rcnt[tid] = 0; rcnt[tid + 256] = 0;
  __syncthreads();
  // phase A: per-row counts from staged (local 9-bit row in bits 17..25)
  for (int i = bstart + tid; i < bend; i += 256)
    atomicAdd(&rcnt[staged[i].x >> 17], 1);
  __syncthreads();
  // phase B: exclusive scan of 512 counters; write global ptr + LDS cursors
  const int lane = tid & 63, wid = tid >> 6;
  int v0 = rcnt[2 * tid], v1 = rcnt[2 * tid + 1];
  int s = v0 + v1;
  int incl = s;
#pragma unroll
  for (int off = 1; off < 64; off <<= 1) {
    int u = __shfl_up(incl, off, 64);
    if (lane >= off) incl += u;
  }
  if (lane == 63) wsum[wid] = incl;
  __syncthreads();
  int woff = 0;
  for (int i = 0; i < wid; ++i) woff += wsum[i];
  int base = bstart + incl - s + woff;
  int rr = r0 + 2 * tid;
  if (rr < n) ptr[rr] = base;
  if (rr + 1 < n) ptr[rr + 1] = base + v0;
  cur[2 * tid] = base;
  cur[2 * tid + 1] = base + v0;
  __syncthreads();
  // phase C: place edges at exact CSR positions
  for (int i = bstart + tid; i < bend; i += 256) {
    int2 e = staged[i];
    int pos = atomicAdd(&cur[e.x >> 17], 1);
    sorted[pos] = make_int2(e.x & 0x1FFFF, e.y);
  }
}

// ---------------- SpMM (CSR, half8 gather) + support blend -> S fp16 ----------------
// one row per wave: 8 edge slots x 8 feature groups (8 feats, 16B loads).
__global__ __launch_bounds__(256) void k_spmm_csr(
    const int* __restrict__ ptr, const int2* __restrict__ sorted,
    const half8* __restrict__ hh, const half8* __restrict__ h0h,
    half8* __restrict__ Sh, int n) {
  const int r = blockIdx.x * 4 + (threadIdx.x >> 6);
  if (r >= n) return;
  const int lane = threadIdx.x & 63;
  const int sub = lane >> 3;       // edge slot 0..7
  const int fl = lane & 7;         // feature group -> feats fl*8..fl*8+7
  const int start = ptr[r], end = ptr[r + 1];
  float acc[8] = {};
  for (int e = start + sub; e < end; e += 8) {
    int2 cw = sorted[e];
    float wv = __int_as_float(cw.y);
    half8 hv = hh[(size_t)cw.x * 8 + fl];
#pragma unroll
    for (int j = 0; j < 8; ++j) acc[j] += wv * (float)hv[j];
  }
#pragma unroll
  for (int off = 8; off < 64; off <<= 1)
#pragma unroll
    for (int j = 0; j < 8; ++j) acc[j] += __shfl_xor(acc[j], off, 64);
  if (sub == 0) {
    half8 h0v = h0h[(size_t)r * 8 + fl];
    half8 o;
#pragma unroll
    for (int j = 0; j < 8; ++j)
      o[j] = (_Float16)(0.9f * acc[j] + 0.1f * (float)h0v[j]);
    Sh[(size_t)r * 8 + fl] = o;
  }
}

// ---------------- h = relu(beta*(S@Wl) + (1-beta)*S) -> fp16 (+fp32 last) ----------------
__global__ __launch_bounds__(256) void k_layer(
    const half8* __restrict__ Sh, const float* __restrict__ Wl,
    float* __restrict__ Af, half4* __restrict__ hout,
    float beta, int n, int write_f32) {
  __shared__ __align__(16) float st[64 * 68];   // transposed [k][r], swizzled
  __shared__ __align__(16) float ws[64 * 64];
  const int tid = threadIdx.x;
  const int row0 = blockIdx.x * 64;
#pragma unroll
  for (int t = 0; t < 2; ++t) {
    int idx = tid + t * 256;          // 0..511
    int q = idx & 7;                  // feat-group of 8
    int r = idx >> 3;                 // 0..63
    int gr = row0 + r; if (gr >= n) gr = n - 1;
    half8 v = Sh[(size_t)gr * 8 + q];
#pragma unroll
    for (int jj = 0; jj < 8; ++jj) {
      int k = q * 8 + jj;
      int rr = r ^ (((k >> 2) & 7) << 2);
      st[k * 68 + rr] = (float)v[jj];
    }
  }
#pragma unroll
  for (int t = 0; t < 4; ++t) {
    int idx = tid + t * 256;
    *reinterpret_cast<float4*>(&ws[idx * 4]) = *reinterpret_cast<const float4*>(&Wl[idx * 4]);
  }
  __syncthreads();
  const int cj = (tid & 15) * 4;
  const int ri = (tid >> 4) * 4;
  float acc[4][4] = {};
#pragma unroll 8
  for (int k = 0; k < 64; ++k) {
    const int s = ((k >> 2) & 7) << 2;
    const float4 wv = *reinterpret_cast<const float4*>(&ws[k * 64 + cj]);
    const float4 sv = *reinterpret_cast<const float4*>(&st[k * 68 + (ri ^ s)]);
    const float sa[4] = {sv.x, sv.y, sv.z, sv.w};
    const float wa[4] = {wv.x, wv.y, wv.z, wv.w};
#pragma unroll
    for (int i = 0; i < 4; ++i)
#pragma unroll
      for (int j = 0; j < 4; ++j) acc[i][j] += sa[i] * wa[j];
  }
  const float g = 1.f - beta;
  const int sw = ((tid & 15) & 7) << 2;
#pragma unroll
  for (int i = 0; i < 4; ++i) {
    int gr = row0 + ri + i;
    if (gr < n) {
      float4 o;
      o.x = fmaxf(beta * acc[i][0] + g * st[(cj + 0) * 68 + ((ri + i) ^ sw)], 0.f);
      o.y = fmaxf(beta * acc[i][1] + g * st[(cj + 1) * 68 + ((ri + i) ^ sw)], 0.f);
      o.z = fmaxf(beta * acc[i][2] + g * st[(cj + 2) * 68 + ((ri + i) ^ sw)], 0.f);
      o.w = fmaxf(beta * acc[i][3] + g * st[(cj + 3) * 68 + ((ri + i) ^ sw)], 0.f);
      half4 hv; hv.x = (_Float16)o.x; hv.y = (_Float16)o.y;
      hv.z = (_Float16)o.z; hv.w = (_Float16)o.w;
      hout[(size_t)gr * 16 + (cj >> 2)] = hv;
      if (write_f32) *reinterpret_cast<float4*>(&Af[(size_t)gr * NHID + cj]) = o;
    }
  }
}

// ---------------- out = log_softmax(h @ W_out + b_out) ----------------
__global__ __launch_bounds__(256) void k_out(
    const float* __restrict__ h, const float* __restrict__ Wo,
    const float* __restrict__ bo, float* __restrict__ out, int n) {
  const int lane = threadIdx.x & 63;
  const int r = blockIdx.x * 4 + (threadIdx.x >> 6);
  if (r >= n) return;
  const float hv = h[(size_t)r * NHID + lane];
  const int j = (lane < NCLS) ? lane : (NCLS - 1);
  float acc = bo[j];
#pragma unroll 16
  for (int k = 0; k < NHID; ++k) {
    float hk = __shfl(hv, k, 64);
    acc += hk * Wo[k * NCLS + j];
  }
  float v = (lane < NCLS) ? acc : -INFINITY;
  float m = v;
#pragma unroll
  for (int off = 32; off; off >>= 1) m = fmaxf(m, __shfl_xor(m, off, 64));
  float e = (lane < NCLS) ? expf(acc - m) : 0.f;
  float s = e;
#pragma unroll
  for (int off = 32; off; off >>= 1) s += __shfl_xor(s, off, 64);
  if (lane < NCLS) out[(size_t)r * NCLS + lane] = acc - m - logf(s);
}

extern "C" void kernel_launch(void* const* d_in, const int* in_sizes, int n_in,
                              void* d_out, int out_size, void* d_ws, size_t ws_size,
                              hipStream_t stream) {
  const float* x  = (const float*)d_in[0];
  const int* row  = (const int*)d_in[1];
  const int* col  = (const int*)d_in[2];
  const float* ew = (const float*)d_in[3];
  const float* Wi = (const float*)d_in[4];
  const float* bi = (const float*)d_in[5];
  const float* Wc = (const float*)d_in[6];
  const float* Wo = (const float*)d_in[7];
  const float* bo = (const float*)d_in[8];
  float* out = (float*)d_out;

  const int n = in_sizes[0] / FIN;   // 100000
  const int E = in_sizes[1];         // 3200000

  // workspace layout (~103 MB)
  half8* h0h   = (half8*)d_ws;                          // n*64 f16
  half8* hhA   = h0h + (size_t)n * 8;                   // n*64 f16
  half8* hhB   = hhA + (size_t)n * 8;                   // n*64 f16
  half8* Sh    = hhB + (size_t)n * 8;                   // n*64 f16 (S buffer)
  float* A     = (float*)(Sh + (size_t)n * 8);          // n*64 f32 final h; aliased staged
  int2*  staged= (int2*)A;                              // E int2 (consumed before layers)
  int2*  sorted= (int2*)(A + (size_t)n * NHID);         // E int2
  int*   ptr   = (int*)(sorted + E);                    // n+1
  int*   ccnt  = ptr + (n + 1);                         // 256
  int*   cbase = ccnt + 256;                            // 257
  int*   bcur  = cbase + 257;                           // 256

  const int nbC = (n + CROWS - 1) >> CSHIFT;            // 196
  const int nPB = (E + PTILE - 1) / PTILE;              // 196
  dim3 blk(256);

  // ---- CSR build (hierarchical; amortized over 8 SpMM layers) ----
  hipMemsetAsync(ccnt, 0, 256 * sizeof(int), stream);
  k_chist<<<dim3(nPB), blk, 0, stream>>>(row, ccnt, E);
  k_cscan<<<dim3(1), blk, 0, stream>>>(ccnt, cbase, bcur, ptr, nbC, n, E);
  k_part2<<<dim3(nPB), blk, 0, stream>>>(row, col, ew, bcur, staged, E, nbC);
  k_rebin3<<<dim3(nbC), blk, 0, stream>>>(cbase, staged, sorted, ptr, n);

  // ---- dense input projection ----
  k_gemm_in<<<dim3((n + 63) / 64), blk, 0, stream>>>(x, Wi, bi, (half4*)h0h, n);

  // ---- 8 GCNII layers ----
  const half8* hin = h0h;
  for (int l = 0; l < NLAYERS; ++l) {
    half8* hout = (l & 1) ? hhB : hhA;
    k_spmm_csr<<<dim3((n + 3) / 4), blk, 0, stream>>>(ptr, sorted, hin, h0h, Sh, n);
    float beta = logf(0.5f / (float)(l + 1) + 1.f);
    k_layer<<<dim3((n + 63) / 64), blk, 0, stream>>>(
        Sh, Wc + (size_t)l * NHID * NHID, A, (half4*)hout, beta, n,
        (l == NLAYERS - 1) ? 1 : 0);
    hin = hout;
  }
  k_out<<<dim3((n + 3) / 4), blk, 0, stream>>>(A, Wo, bo, out, n);
}